// Round 2
// baseline (443.762 us; speedup 1.0000x reference)
//
#include <hip/hip_runtime.h>

// CNOT permutation on a (d^n, batch) fp32 state vector.
// out[lin(i), :] = x[i, :], lin(i) = i with target digit -> (dt + dc) % d.
// lin is a bijection, so every output element is written exactly once
// (no need to zero d_out despite 0xAA poison).

__global__ __launch_bounds__(256) void cnot_perm_kernel(
    const float* __restrict__ x,
    const int* __restrict__ p_control,
    const int* __restrict__ p_target,
    const int* __restrict__ p_d,
    const int* __restrict__ p_n,
    float* __restrict__ out,
    long long total)          // total elements = d^n * batch (host-known)
{
    const int control = p_control[0];
    const int target  = p_target[0];
    const int d       = p_d[0];
    const int n       = p_n[0];

    // Dn = d^n (n <= ~40, tiny uniform loop; memory-bound kernel)
    long long Dn = 1;
    for (int k = 0; k < n; ++k) Dn *= (long long)d;
    const long long batch = total / Dn;

    const long long stride = (long long)gridDim.x * blockDim.x;
    const long long t0     = (long long)blockIdx.x * blockDim.x + threadIdx.x;

    if (d == 2 && batch == 4) {
        // Fast path: each row is one float4; permutation is a single XOR.
        // lin(i) = i ^ (((i >> sc) & 1) << st)
        const int sc = n - 1 - control;   // bit position of control
        const int st = n - 1 - target;    // bit position of target
        const long long rows = Dn;
        for (long long i = t0; i < rows; i += stride) {
            const long long j = i ^ (((i >> sc) & 1LL) << st);
            const float4 v = *reinterpret_cast<const float4*>(x + (i << 2));
            *reinterpret_cast<float4*>(out + (j << 2)) = v;
        }
    } else {
        // Generic path: scalar per element, integer digit arithmetic.
        long long ptv = 1; for (int k = 0; k < n - 1 - target;  ++k) ptv *= (long long)d;
        long long pcv = 1; for (int k = 0; k < n - 1 - control; ++k) pcv *= (long long)d;
        for (long long e = t0; e < total; e += stride) {
            const long long i   = e / batch;
            const long long col = e - i * batch;
            const long long dt  = (i / ptv) % d;
            const long long dc  = (i / pcv) % d;
            const long long lin = i + (((dt + dc) % d) - dt) * ptv;
            out[lin * batch + col] = x[e];
        }
    }
}

extern "C" void kernel_launch(void* const* d_in, const int* in_sizes, int n_in,
                              void* d_out, int out_size, void* d_ws, size_t ws_size,
                              hipStream_t stream) {
    const float* x        = (const float*)d_in[0];
    const int* p_control  = (const int*)d_in[1];
    const int* p_target   = (const int*)d_in[2];
    const int* p_d        = (const int*)d_in[3];
    const int* p_n        = (const int*)d_in[4];
    float* out            = (float*)d_out;

    const long long total = (long long)out_size;   // == in_sizes[0]

    // Memory-bound streaming kernel: 2048 blocks x 256 threads = 524288
    // threads = full chip residency (256 CU x 32 waves x 64 lanes); grid-stride.
    const int block = 256;
    long long want  = (total / 4 + block - 1) / block;  // one thread per row in fast path
    int grid = (int)(want < 2048 ? (want < 1 ? 1 : want) : 2048);

    cnot_perm_kernel<<<grid, block, 0, stream>>>(
        x, p_control, p_target, p_d, p_n, out, total);
}